// Round 2
// baseline (4443.700 us; speedup 1.0000x reference)
//
#include <hip/hip_runtime.h>

#define NTOK  32768
#define NE    8192
#define DIM   256
#define EPSF  5.0e-4f   // candidate band slack (>= 2*delta bound 3.2e-4 + key quantum)
#define DSELQ 4.8e-4f   // ambiguity bound on quantized keys (4.5e-4 + quantum slop)

typedef __attribute__((ext_vector_type(8))) short short8;
typedef __attribute__((ext_vector_type(4))) float f32x4;

static __device__ __forceinline__ unsigned pk32(float f) {
  unsigned u = __float_as_uint(f);
  return (u & 0x80000000u) ? ~u : (u | 0x80000000u);
}
static __device__ __forceinline__ float upk32(unsigned p) {
  unsigned u = (p & 0x80000000u) ? (p & 0x7fffffffu) : ~p;
  return __uint_as_float(u);
}
static __device__ __forceinline__ unsigned long long pk64(float s, int idx) {
  return ((unsigned long long)pk32(s) << 32) | (unsigned)idx;
}
static __device__ __forceinline__ unsigned short bf16rne(float f) {
  unsigned u = __float_as_uint(f);
  unsigned r = u + 0x7fffu + ((u >> 16) & 1u);
  return (unsigned short)(r >> 16);
}
static __device__ __forceinline__ void gld16(const void* g, void* l) {
  __builtin_amdgcn_global_load_lds(
      (const __attribute__((address_space(1))) unsigned int*)g,
      (__attribute__((address_space(3))) unsigned int*)l, 16, 0, 0);
}
// merge candidate x into sorted pair (b,s)
static __device__ __forceinline__ void mrg1(unsigned& b, unsigned& s, unsigned x) {
  if (x < b) { s = b; b = x; } else if (x < s) { s = x; }
}
// merge sorted pair (pb,ps) into (b,s)
static __device__ __forceinline__ void mrg2(unsigned& b, unsigned& s, unsigned pb, unsigned ps) {
  unsigned nb = b < pb ? b : pb;
  unsigned mx = b < pb ? pb : b;
  unsigned mn = s < ps ? s : ps;
  s = mx < mn ? mx : mn;
  b = nb;
}

// ---------------- K1: prep (z2/e2 pairwise-exact, eb bf16 copy, inits) -------
__global__ __launch_bounds__(256) void vq_prep(const float* __restrict__ z,
                                               const float* __restrict__ emb,
                                               float* __restrict__ e2,
                                               float* __restrict__ z2,
                                               unsigned* __restrict__ work,
                                               unsigned short* __restrict__ eb,
                                               float* __restrict__ loss_slot) {
  int gid = blockIdx.x * 256 + threadIdx.x;
  if (gid == 0) { loss_slot[0] = 0.0f; work[0] = 0u; }

  int wave = gid >> 6;
  int lane = threadIdx.x & 63;
  int row = wave * 16 + (lane >> 2);            // 0..40959
  int sub = lane & 3;
  int q = sub & 1, h = sub >> 1;

  const bool is_e = (row >= NTOK);
  const float* src = is_e ? (emb + (size_t)(row - NTOK) * DIM)
                          : (z + (size_t)row * DIM);
  unsigned short* dst = is_e ? (eb + (size_t)(row - NTOK) * DIM) : (unsigned short*)0;
  const float4* p = reinterpret_cast<const float4*>(src + h * 128 + q * 4);

  float r0, r1, r2, r3, s;
  {
    #pragma clang fp contract(off)
    r0 = 0.0f; r1 = 0.0f; r2 = 0.0f; r3 = 0.0f;
    #pragma unroll
    for (int t = 0; t < 16; t++) {
      float4 v = p[2 * t];
      if (is_e) {
        ushort4 w;
        w.x = bf16rne(v.x); w.y = bf16rne(v.y); w.z = bf16rne(v.z); w.w = bf16rne(v.w);
        *reinterpret_cast<ushort4*>(dst + h * 128 + q * 4 + t * 8) = w;
      }
      float q0 = v.x * v.x, q1 = v.y * v.y, q2 = v.z * v.z, q3 = v.w * v.w;
      r0 = r0 + q0; r1 = r1 + q1; r2 = r2 + q2; r3 = r3 + q3;
    }
    s = (r0 + r1) + (r2 + r3);
    s = s + __shfl_xor(s, 1, 64);
    s = s + __shfl_xor(s, 2, 64);
  }
  if (sub == 0) {
    if (is_e) e2[row - NTOK] = s;
    else      z2[row] = s;
  }
}

// ---------------- K2: single-pass bf16 MFMA scoring, top-2 per 128-tile ------
// A (z-tile) reg-staged fp32->bf16 into swizzled LDS (same layout as eb path);
// B (emb) via global_load_lds with pre-swizzled global source.  Epilogue emits
// per (token, e-tile) the two smallest 26-bit entries (key19<<7 | col7) packed
// into one u64 -> best2[ey][token]  (coalesced 1KB stores per block).
__global__ __launch_bounds__(256, 2) void vq_score(const float* __restrict__ z,
                                                   const unsigned short* __restrict__ eb,
                                                   const float* __restrict__ e2,
                                                   unsigned long long* __restrict__ best2) {
  __shared__ unsigned short Ab[128 * 64];
  __shared__ unsigned short Bb[128 * 64];
  __shared__ unsigned sbuf[128][8];
  __shared__ unsigned ssec[128][8];

  const int tid = threadIdx.x;
  const int t0 = blockIdx.x * 128;
  const int e0 = blockIdx.y * 128;
  const int lane = tid & 63;
  const int wv = tid >> 6;
  const int wm = wv & 1, wn = wv >> 1;

  f32x4 acc[4][4];
  #pragma unroll
  for (int i = 0; i < 4; i++)
    #pragma unroll
    for (int j = 0; j < 4; j++) acc[i][j] = (f32x4)0.0f;

  // B staging (gld16, linear LDS dest + inverse-swizzled global source):
  const int r0 = tid >> 3;
  const int sq = (tid & 7) ^ (r0 & 7);
  const size_t gb = (size_t)(e0 + r0) * DIM + sq * 8;
  char* lb0 = (char*)Bb + tid * 16;

  // A staging (fp32 z -> bf16, per-lane swizzled ds_write_b128):
  const int ar = tid >> 1;            // 0..127 token row
  const int ah = tid & 1;             // k-half (32 floats)
  const float* zsrc = z + (size_t)(t0 + ar) * DIM + ah * 32;
  char* aw = (char*)Ab + ar * 128;
  const int akey = ar & 7;

  // fragment reads: row = w*64 + f*16 + la  ->  row&7 == la&7 (loop-invariant)
  const int la = lane & 15, lq = lane >> 4;
  const int key = la & 7;
  const char* Abase = (const char*)Ab + (wm * 64 + la) * 128;
  const char* Bbase = (const char*)Bb + (wn * 64 + la) * 128;

  for (int kc = 0; kc < DIM; kc += 64) {
    __syncthreads();
    #pragma unroll
    for (int i = 0; i < 4; i++)
      gld16(eb + gb + kc + (size_t)(i * 32) * DIM, lb0 + i * 4096);
    {
      const float4* zp = reinterpret_cast<const float4*>(zsrc + kc);
      float4 va[8];
      #pragma unroll
      for (int j = 0; j < 8; j++) va[j] = zp[j];
      #pragma unroll
      for (int j = 0; j < 4; j++) {
        short8 w;
        w[0] = (short)bf16rne(va[2 * j].x);
        w[1] = (short)bf16rne(va[2 * j].y);
        w[2] = (short)bf16rne(va[2 * j].z);
        w[3] = (short)bf16rne(va[2 * j].w);
        w[4] = (short)bf16rne(va[2 * j + 1].x);
        w[5] = (short)bf16rne(va[2 * j + 1].y);
        w[6] = (short)bf16rne(va[2 * j + 1].z);
        w[7] = (short)bf16rne(va[2 * j + 1].w);
        *reinterpret_cast<short8*>(aw + (((ah << 2) + j) ^ akey) * 16) = w;
      }
    }
    __syncthreads();
    #pragma unroll
    for (int ks = 0; ks < 2; ks++) {
      const int q = ((ks * 4 + lq) ^ key) * 16;
      short8 a[4], b[4];
      #pragma unroll
      for (int f = 0; f < 4; f++) {
        a[f] = *reinterpret_cast<const short8*>(Abase + f * 2048 + q);
        b[f] = *reinterpret_cast<const short8*>(Bbase + f * 2048 + q);
      }
      #pragma unroll
      for (int fi = 0; fi < 4; fi++)
        #pragma unroll
        for (int fj = 0; fj < 4; fj++)
          acc[fi][fj] = __builtin_amdgcn_mfma_f32_16x16x32_bf16(a[fi], b[fj], acc[fi][fj], 0, 0, 0);
    }
  }

  float e2c[4];
  #pragma unroll
  for (int fj = 0; fj < 4; fj++)
    e2c[fj] = e2[e0 + wn * 64 + fj * 16 + la];

  // ---- epilogue: per-token top-2 within this 128-wide e-tile ----
  const unsigned colbase = (unsigned)(wn * 64 + la);
  #pragma unroll
  for (int fi = 0; fi < 4; fi++) {
    #pragma unroll
    for (int r = 0; r < 4; r++) {
      unsigned b = 0xFFFFFFFFu, s2 = 0xFFFFFFFFu;
      #pragma unroll
      for (int fj = 0; fj < 4; fj++) {
        float sc = fmaf(-2.0f, acc[fi][fj][r], e2c[fj]);
        unsigned e = ((pk32(sc) >> 13) << 7) | (colbase + (unsigned)(fj * 16));
        mrg1(b, s2, e);
      }
      #pragma unroll
      for (int off = 1; off < 4; off <<= 1) {
        unsigned ob = __shfl_xor(b, off, 64);
        unsigned os = __shfl_xor(s2, off, 64);
        mrg2(b, s2, ob, os);
      }
      if ((la & 3) == 0) {
        int tl = wm * 64 + fi * 16 + (lq << 2) + r;
        int slot = wn * 4 + (la >> 2);
        sbuf[tl][slot] = b;
        ssec[tl][slot] = s2;
      }
    }
  }
  __syncthreads();
  if (tid < 128) {
    unsigned B = 0xFFFFFFFFu, S = 0xFFFFFFFFu;
    #pragma unroll
    for (int p = 0; p < 8; p++) mrg2(B, S, sbuf[tid][p], ssec[tid][p]);
    best2[(size_t)blockIdx.y * NTOK + t0 + tid] = ((unsigned long long)B << 32) | S;
  }
}

// ---------------- K3a: merge 64 tiles/token; route ambiguous to worklist -----
__global__ __launch_bounds__(256) void vq_reduce(const unsigned long long* __restrict__ best2,
                                                 unsigned* __restrict__ winners,
                                                 unsigned* __restrict__ work) {
  int t = blockIdx.x * 256 + threadIdx.x;
  unsigned b = 0xFFFFFFFFu, s = 0xFFFFFFFFu;
  int bey = 0;
  #pragma unroll 8
  for (int ey = 0; ey < 64; ey++) {
    unsigned long long v = best2[(size_t)ey * NTOK + t];
    unsigned hb = (unsigned)(v >> 32), lb = (unsigned)v;
    if (hb < b) { s = b; b = hb; bey = ey; }
    else if (hb < s) { s = hb; }
    if (lb < s) s = lb;          // lb >= hb by construction
  }
  float fb = upk32((b >> 7) << 13);
  float fs = upk32((s >> 7) << 13);
  if (fs > fb + DSELQ) winners[t] = (unsigned)(bey * 128) + (b & 127u);
  else work[1 + atomicAdd(&work[0], 1u)] = (unsigned)t;
}

// ---------------- K3b: exact fp32 resolution for ambiguous tokens ------------
// One wave per token; lane ly owns e-tile ly's two stored entries.  If any
// tile's SECOND entry is inside the band (possible hidden rank-3 candidate),
// fall back to exact full scan; else the in-band stored set is provably
// complete and we exact-check it.
__global__ __launch_bounds__(64) void vq_chain(const float* __restrict__ z,
                                               const float* __restrict__ emb,
                                               const float* __restrict__ z2,
                                               const float* __restrict__ e2,
                                               const unsigned long long* __restrict__ best2,
                                               const unsigned* __restrict__ work,
                                               unsigned* __restrict__ winners) {
  __shared__ float zr[256];
  const int lane = threadIdx.x;
  const int nw = (int)work[0];

  for (int i = blockIdx.x; i < nw; i += gridDim.x) {
    int t = (int)work[1 + i];
    float4 zv = reinterpret_cast<const float4*>(z + (size_t)t * DIM)[lane];
    *reinterpret_cast<float4*>(&zr[lane * 4]) = zv;
    __syncthreads();
    const float z2t = z2[t];

    unsigned long long v = best2[(size_t)lane * NTOK + t];
    unsigned hb = (unsigned)(v >> 32), lb = (unsigned)v;

    unsigned bm = hb;
    #pragma unroll
    for (int off = 1; off < 64; off <<= 1) {
      unsigned o = __shfl_xor(bm, off, 64);
      bm = o < bm ? o : bm;
    }
    float fb = upk32((bm >> 7) << 13);
    unsigned bandkey = pk32(fb + EPSF) >> 13;
    bool danger = __any((int)((lb >> 7) <= bandkey));

    unsigned long long best = ~0ull;
    if (!danger) {
      #pragma unroll
      for (int which = 0; which < 2; which++) {
        unsigned e = which ? lb : hb;
        if ((e >> 7) <= bandkey) {
          int cidx = lane * 128 + (int)(e & 127u);
          const float* er = emb + (size_t)cidx * DIM;
          float m;
          {
            #pragma clang fp contract(off)
            m = 0.0f;
            #pragma unroll 8
            for (int k = 0; k < DIM; k++) m = fmaf(2.0f * zr[k], er[k], m);
            float sc = (z2t - m) + e2[cidx];
            unsigned long long kk = pk64(sc, cidx);
            best = kk < best ? kk : best;
          }
        }
      }
    } else {
      for (int cb = 0; cb < NE / 64; cb++) {
        int cidx = cb * 64 + lane;
        const float* er = emb + (size_t)cidx * DIM;
        float m;
        {
          #pragma clang fp contract(off)
          m = 0.0f;
          #pragma unroll 8
          for (int k = 0; k < DIM; k++) m = fmaf(2.0f * zr[k], er[k], m);
          float sc = (z2t - m) + e2[cidx];
          unsigned long long kk = pk64(sc, cidx);
          best = kk < best ? kk : best;
        }
      }
    }
    #pragma unroll
    for (int off = 32; off > 0; off >>= 1) {
      unsigned long long o = __shfl_xor(best, off, 64);
      best = o < best ? o : best;
    }
    if (lane == 0) winners[t] = (unsigned)(best & 0xffffffffu);
    __syncthreads();
  }
}

// ---------------- K4: gather zq = emb[winner], idx, loss ---------------------
__global__ __launch_bounds__(256) void vq_emit(const float* __restrict__ z,
                                               const float* __restrict__ emb,
                                               const unsigned* __restrict__ winners,
                                               float* __restrict__ out_zq,
                                               float* __restrict__ out_loss,
                                               float* __restrict__ out_idx) {
  __shared__ float lsum[4];
  const int wid = threadIdx.x >> 6;
  const int lane = threadIdx.x & 63;
  const int tbase = blockIdx.x * 16 + wid * 4;
  float s_acc = 0.0f;
  #pragma unroll
  for (int it = 0; it < 4; it++) {
    int t = tbase + it;
    unsigned idx = winners[t];
    float4 e = reinterpret_cast<const float4*>(emb + (size_t)idx * DIM)[lane];
    float4 zz = reinterpret_cast<const float4*>(z + (size_t)t * DIM)[lane];
    reinterpret_cast<float4*>(out_zq + (size_t)t * DIM)[lane] = e;
    float dx = e.x - zz.x, dy = e.y - zz.y, dz = e.z - zz.z, dw = e.w - zz.w;
    s_acc += dx * dx + dy * dy + dz * dz + dw * dw;
    if (lane == 0) out_idx[t] = (float)idx;
  }
  #pragma unroll
  for (int off = 32; off > 0; off >>= 1) s_acc += __shfl_down(s_acc, off, 64);
  if (lane == 0) lsum[wid] = s_acc;
  __syncthreads();
  if (threadIdx.x == 0) {
    float tot = (lsum[0] + lsum[1] + lsum[2] + lsum[3]) * (1.25f / 8388608.0f);
    atomicAdd(out_loss, tot);
  }
}

// ====================== round-3 verified fallback path =======================
#define BT 128
#define BE 128
#define BK 32
#define LDW 132

__global__ __launch_bounds__(256) void fb_init(const float* __restrict__ z,
                                               const float* __restrict__ emb,
                                               float* __restrict__ e2,
                                               float* __restrict__ z2,
                                               unsigned long long* __restrict__ k1,
                                               float* __restrict__ loss_slot) {
  int gid = blockIdx.x * 256 + threadIdx.x;
  if (gid < NTOK) k1[gid] = ~0ull;
  if (gid == 0) loss_slot[0] = 0.0f;
  int wave = gid >> 6;
  int lane = threadIdx.x & 63;
  int row = wave * 16 + (lane >> 2);
  int sub = lane & 3;
  int q = sub & 1, h = sub >> 1;
  const float* src = (row < NTOK) ? (z + (size_t)row * DIM)
                                  : (emb + (size_t)(row - NTOK) * DIM);
  const float4* p = reinterpret_cast<const float4*>(src + h * 128 + q * 4);
  float r0, r1, r2, r3, s;
  {
    #pragma clang fp contract(off)
    r0 = 0.0f; r1 = 0.0f; r2 = 0.0f; r3 = 0.0f;
    #pragma unroll
    for (int t = 0; t < 16; t++) {
      float4 v = p[2 * t];
      float q0 = v.x * v.x, q1 = v.y * v.y, q2 = v.z * v.z, q3 = v.w * v.w;
      r0 = r0 + q0; r1 = r1 + q1; r2 = r2 + q2; r3 = r3 + q3;
    }
    s = (r0 + r1) + (r2 + r3);
    s = s + __shfl_xor(s, 1, 64);
    s = s + __shfl_xor(s, 2, 64);
  }
  if (sub == 0) {
    if (row < NTOK) z2[row] = s;
    else            e2[row - NTOK] = s;
  }
}

__global__ __launch_bounds__(256, 4) void fb_score(const float* __restrict__ z,
                                                   const float* __restrict__ emb,
                                                   const float* __restrict__ e2,
                                                   const float* __restrict__ z2,
                                                   unsigned long long* __restrict__ k1) {
  __shared__ float As[BK][LDW];
  __shared__ float Bs[BK][LDW];
  __shared__ unsigned long long mkey[BT];
  const int tid = threadIdx.x;
  const int t0 = blockIdx.x * BT;
  const int e0 = blockIdx.y * BE;
  const int tx = tid & 15;
  const int ty = tid >> 4;
  if (tid < BT) mkey[tid] = ~0ull;
  float acc[8][8];
  #pragma unroll
  for (int i = 0; i < 8; i++)
    #pragma unroll
    for (int j = 0; j < 8; j++) acc[i][j] = 0.0f;
  const float* __restrict__ zt = z + (size_t)t0 * DIM;
  const float* __restrict__ et = emb + (size_t)e0 * DIM;
  for (int kc = 0; kc < DIM; kc += BK) {
    __syncthreads();
    #pragma unroll
    for (int i = 0; i < 4; i++) {
      int f = tid + i * 256;
      int row = f >> 3;
      int kq = f & 7;
      const float4 va = *reinterpret_cast<const float4*>(zt + row * DIM + kc + kq * 4);
      const float4 vb = *reinterpret_cast<const float4*>(et + row * DIM + kc + kq * 4);
      int k = kq * 4;
      As[k + 0][row] = va.x * 2.0f; As[k + 1][row] = va.y * 2.0f;
      As[k + 2][row] = va.z * 2.0f; As[k + 3][row] = va.w * 2.0f;
      Bs[k + 0][row] = vb.x; Bs[k + 1][row] = vb.y;
      Bs[k + 2][row] = vb.z; Bs[k + 3][row] = vb.w;
    }
    __syncthreads();
    #pragma unroll 4
    for (int k = 0; k < BK; k++) {
      float a[8], b[8];
      *(float4*)&a[0] = *(const float4*)&As[k][ty * 8];
      *(float4*)&a[4] = *(const float4*)&As[k][ty * 8 + 4];
      *(float4*)&b[0] = *(const float4*)&Bs[k][tx * 8];
      *(float4*)&b[4] = *(const float4*)&Bs[k][tx * 8 + 4];
      #pragma unroll
      for (int i = 0; i < 8; i++)
        #pragma unroll
        for (int j = 0; j < 8; j++)
          acc[i][j] = fmaf(a[i], b[j], acc[i][j]);
    }
  }
  float e2c[8], z2t[8];
  *(float4*)&e2c[0] = *(const float4*)(e2 + e0 + tx * 8);
  *(float4*)&e2c[4] = *(const float4*)(e2 + e0 + tx * 8 + 4);
  *(float4*)&z2t[0] = *(const float4*)(z2 + t0 + ty * 8);
  *(float4*)&z2t[4] = *(const float4*)(z2 + t0 + ty * 8 + 4);
  {
    #pragma clang fp contract(off)
    #pragma unroll
    for (int i = 0; i < 8; i++) {
      int trow = ty * 8 + i;
      unsigned long long best = ~0ull;
      #pragma unroll
      for (int j = 0; j < 8; j++) {
        float t1 = z2t[i] - acc[i][j];
        float s = t1 + e2c[j];
        unsigned long long kk = pk64(s, e0 + tx * 8 + j);
        best = kk < best ? kk : best;
      }
      atomicMin(&mkey[trow], best);
    }
  }
  __syncthreads();
  if (tid < BT) atomicMin(&k1[t0 + tid], mkey[tid]);
}

__global__ __launch_bounds__(256) void fb_out(const float* __restrict__ z,
                                              const float* __restrict__ emb,
                                              const unsigned long long* __restrict__ k1,
                                              float* __restrict__ out_zq,
                                              float* __restrict__ out_loss,
                                              float* __restrict__ out_idx) {
  __shared__ float lsum[4];
  const int wid = threadIdx.x >> 6;
  const int lane = threadIdx.x & 63;
  const int tbase = blockIdx.x * 16 + wid * 4;
  float s_acc = 0.0f;
  #pragma unroll
  for (int it = 0; it < 4; it++) {
    int t = tbase + it;
    unsigned idx = (unsigned)(k1[t] & 0xffffffffu);
    float4 e = reinterpret_cast<const float4*>(emb + (size_t)idx * DIM)[lane];
    float4 zz = reinterpret_cast<const float4*>(z + (size_t)t * DIM)[lane];
    reinterpret_cast<float4*>(out_zq + (size_t)t * DIM)[lane] = e;
    float dx = e.x - zz.x, dy = e.y - zz.y, dz = e.z - zz.z, dw = e.w - zz.w;
    s_acc += dx * dx + dy * dy + dz * dz + dw * dw;
    if (lane == 0) out_idx[t] = (float)idx;
  }
  #pragma unroll
  for (int off = 32; off > 0; off >>= 1) s_acc += __shfl_down(s_acc, off, 64);
  if (lane == 0) lsum[wid] = s_acc;
  __syncthreads();
  if (threadIdx.x == 0) {
    float tot = (lsum[0] + lsum[1] + lsum[2] + lsum[3]) * (1.25f / 8388608.0f);
    atomicAdd(out_loss, tot);
  }
}

// ============================== launcher =====================================
extern "C" void kernel_launch(void* const* d_in, const int* in_sizes, int n_in,
                              void* d_out, int out_size, void* d_ws, size_t ws_size,
                              hipStream_t stream) {
  const float* z = (const float*)d_in[0];
  const float* emb = (const float*)d_in[1];
  float* out = (float*)d_out;
  float* out_zq = out;
  float* out_loss = out + (size_t)NTOK * DIM;
  float* out_idx = out_loss + 1;

  // ws: e2 | z2 | best2[64][NTOK]u64 | work(1+NTOK) | winners | eb
  const size_t OFF_Z2   = 32768;
  const size_t OFF_B2   = 163840;
  const size_t OFF_WORK = OFF_B2 + (size_t)64 * NTOK * 8;      // 16941056
  const size_t OFF_WIN  = OFF_WORK + 4 + 4 * (size_t)NTOK;     // 17072132
  const size_t OFF_EB   = (OFF_WIN + 4 * (size_t)NTOK + 15) & ~(size_t)15;  // 17203216
  const size_t REQ      = OFF_EB + (size_t)NE * DIM * 2;       // 21397520

  if (ws_size >= REQ) {
    float* e2 = (float*)d_ws;
    float* z2 = (float*)((char*)d_ws + OFF_Z2);
    unsigned long long* best2 = (unsigned long long*)((char*)d_ws + OFF_B2);
    unsigned* work = (unsigned*)((char*)d_ws + OFF_WORK);
    unsigned* winners = (unsigned*)((char*)d_ws + OFF_WIN);
    unsigned short* eb = (unsigned short*)((char*)d_ws + OFF_EB);

    hipLaunchKernelGGL(vq_prep, dim3(640), dim3(256), 0, stream,
                       z, emb, e2, z2, work, eb, out_loss);
    hipLaunchKernelGGL(vq_score, dim3(NTOK / 128, NE / 128), dim3(256), 0, stream,
                       z, eb, e2, best2);
    hipLaunchKernelGGL(vq_reduce, dim3(NTOK / 256), dim3(256), 0, stream,
                       best2, winners, work);
    hipLaunchKernelGGL(vq_chain, dim3(4096), dim3(64), 0, stream,
                       z, emb, z2, e2, best2, work, winners);
    hipLaunchKernelGGL(vq_emit, dim3(NTOK / 16), dim3(256), 0, stream,
                       z, emb, winners, out_zq, out_loss, out_idx);
  } else {
    float* e2 = (float*)d_ws;
    float* z2 = (float*)((char*)d_ws + 32768);
    unsigned long long* k1 = (unsigned long long*)((char*)d_ws + 262144);
    hipLaunchKernelGGL(fb_init, dim3(640), dim3(256), 0, stream,
                       z, emb, e2, z2, k1, out_loss);
    hipLaunchKernelGGL(fb_score, dim3(NTOK / BT, NE / BE), dim3(256), 0, stream,
                       z, emb, e2, z2, k1);
    hipLaunchKernelGGL(fb_out, dim3(NTOK / 16), dim3(256), 0, stream,
                       z, emb, k1, out_zq, out_loss, out_idx);
  }
}

// Round 4
// 907.689 us; speedup vs baseline: 4.8956x; 4.8956x over previous
//
#include <hip/hip_runtime.h>

#define NTOK  32768
#define NE    8192
#define DIM   256
#define EPSF  5.0e-4f   // candidate band slack (>= 2*delta bound 3.2e-4 + key quantum)
#define DSELQ 4.8e-4f   // ambiguity bound on quantized keys (4.5e-4 + quantum slop)

typedef __attribute__((ext_vector_type(8))) short short8;
typedef __attribute__((ext_vector_type(4))) float f32x4;

static __device__ __forceinline__ unsigned pk32(float f) {
  unsigned u = __float_as_uint(f);
  return (u & 0x80000000u) ? ~u : (u | 0x80000000u);
}
static __device__ __forceinline__ float upk32(unsigned p) {
  unsigned u = (p & 0x80000000u) ? (p & 0x7fffffffu) : ~p;
  return __uint_as_float(u);
}
static __device__ __forceinline__ unsigned long long pk64(float s, int idx) {
  return ((unsigned long long)pk32(s) << 32) | (unsigned)idx;
}
static __device__ __forceinline__ unsigned short bf16rne(float f) {
  unsigned u = __float_as_uint(f);
  unsigned r = u + 0x7fffu + ((u >> 16) & 1u);
  return (unsigned short)(r >> 16);
}
static __device__ __forceinline__ void gld16(const void* g, void* l) {
  __builtin_amdgcn_global_load_lds(
      (const __attribute__((address_space(1))) unsigned int*)g,
      (__attribute__((address_space(3))) unsigned int*)l, 16, 0, 0);
}
// merge candidate x into sorted pair (b,s)
static __device__ __forceinline__ void mrg1(unsigned& b, unsigned& s, unsigned x) {
  if (x < b) { s = b; b = x; } else if (x < s) { s = x; }
}
// merge sorted pair (pb,ps) into (b,s)
static __device__ __forceinline__ void mrg2(unsigned& b, unsigned& s, unsigned pb, unsigned ps) {
  unsigned nb = b < pb ? b : pb;
  unsigned mx = b < pb ? pb : b;
  unsigned mn = s < ps ? s : ps;
  s = mx < mn ? mx : mn;
  b = nb;
}
// exact fp32 score key for code cidx vs LDS-staged z row (k-order fmaf chain,
// identical arithmetic to the round-1-verified scalar version; float4 loads)
static __device__ __forceinline__ unsigned long long exdot(const float* __restrict__ emb,
                                                           const float* zr, float z2t,
                                                           const float* __restrict__ e2,
                                                           int cidx) {
  {
    #pragma clang fp contract(off)
    const float* er = emb + (size_t)cidx * DIM;
    float m = 0.0f;
    #pragma unroll 8
    for (int k4 = 0; k4 < DIM / 4; k4++) {
      float4 v = reinterpret_cast<const float4*>(er)[k4];
      m = fmaf(2.0f * zr[4 * k4 + 0], v.x, m);
      m = fmaf(2.0f * zr[4 * k4 + 1], v.y, m);
      m = fmaf(2.0f * zr[4 * k4 + 2], v.z, m);
      m = fmaf(2.0f * zr[4 * k4 + 3], v.w, m);
    }
    float sc = (z2t - m) + e2[cidx];
    return pk64(sc, cidx);
  }
}

// ---------------- K1: prep (z2/e2 pairwise-exact, eb bf16 copy, inits) -------
__global__ __launch_bounds__(256) void vq_prep(const float* __restrict__ z,
                                               const float* __restrict__ emb,
                                               float* __restrict__ e2,
                                               float* __restrict__ z2,
                                               unsigned* __restrict__ work,
                                               unsigned short* __restrict__ eb,
                                               float* __restrict__ loss_slot) {
  int gid = blockIdx.x * 256 + threadIdx.x;
  if (gid == 0) { loss_slot[0] = 0.0f; work[0] = 0u; }

  int wave = gid >> 6;
  int lane = threadIdx.x & 63;
  int row = wave * 16 + (lane >> 2);            // 0..40959
  int sub = lane & 3;
  int q = sub & 1, h = sub >> 1;

  const bool is_e = (row >= NTOK);
  const float* src = is_e ? (emb + (size_t)(row - NTOK) * DIM)
                          : (z + (size_t)row * DIM);
  unsigned short* dst = is_e ? (eb + (size_t)(row - NTOK) * DIM) : (unsigned short*)0;
  const float4* p = reinterpret_cast<const float4*>(src + h * 128 + q * 4);

  float r0, r1, r2, r3, s;
  {
    #pragma clang fp contract(off)
    r0 = 0.0f; r1 = 0.0f; r2 = 0.0f; r3 = 0.0f;
    #pragma unroll
    for (int t = 0; t < 16; t++) {
      float4 v = p[2 * t];
      if (is_e) {
        ushort4 w;
        w.x = bf16rne(v.x); w.y = bf16rne(v.y); w.z = bf16rne(v.z); w.w = bf16rne(v.w);
        *reinterpret_cast<ushort4*>(dst + h * 128 + q * 4 + t * 8) = w;
      }
      float q0 = v.x * v.x, q1 = v.y * v.y, q2 = v.z * v.z, q3 = v.w * v.w;
      r0 = r0 + q0; r1 = r1 + q1; r2 = r2 + q2; r3 = r3 + q3;
    }
    s = (r0 + r1) + (r2 + r3);
    s = s + __shfl_xor(s, 1, 64);
    s = s + __shfl_xor(s, 2, 64);
  }
  if (sub == 0) {
    if (is_e) e2[row - NTOK] = s;
    else      z2[row] = s;
  }
}

// ---------------- K2: single-pass bf16 MFMA scoring, top-2 per 128-tile ------
// A (z-tile) reg-staged fp32->bf16 into swizzled LDS; B (emb) via
// global_load_lds with pre-swizzled global source.  Epilogue emits per
// (token, e-tile) the two smallest 26-bit entries (key19<<7 | col7) packed
// into one u64 -> best2[ey][token]  (coalesced 1KB stores per block).
__global__ __launch_bounds__(256, 2) void vq_score(const float* __restrict__ z,
                                                   const unsigned short* __restrict__ eb,
                                                   const float* __restrict__ e2,
                                                   unsigned long long* __restrict__ best2) {
  __shared__ unsigned short Ab[128 * 64];
  __shared__ unsigned short Bb[128 * 64];
  __shared__ unsigned sbuf[128][8];
  __shared__ unsigned ssec[128][8];

  const int tid = threadIdx.x;
  const int t0 = blockIdx.x * 128;
  const int e0 = blockIdx.y * 128;
  const int lane = tid & 63;
  const int wv = tid >> 6;
  const int wm = wv & 1, wn = wv >> 1;

  f32x4 acc[4][4];
  #pragma unroll
  for (int i = 0; i < 4; i++)
    #pragma unroll
    for (int j = 0; j < 4; j++) acc[i][j] = (f32x4)0.0f;

  // B staging (gld16, linear LDS dest + inverse-swizzled global source):
  const int r0 = tid >> 3;
  const int sq = (tid & 7) ^ (r0 & 7);
  const size_t gb = (size_t)(e0 + r0) * DIM + sq * 8;
  char* lb0 = (char*)Bb + tid * 16;

  // A staging (fp32 z -> bf16, per-lane swizzled ds_write_b128):
  const int ar = tid >> 1;            // 0..127 token row
  const int ah = tid & 1;             // k-half (32 floats)
  const float* zsrc = z + (size_t)(t0 + ar) * DIM + ah * 32;
  char* aw = (char*)Ab + ar * 128;
  const int akey = ar & 7;

  // fragment reads: row = w*64 + f*16 + la  ->  row&7 == la&7 (loop-invariant)
  const int la = lane & 15, lq = lane >> 4;
  const int key = la & 7;
  const char* Abase = (const char*)Ab + (wm * 64 + la) * 128;
  const char* Bbase = (const char*)Bb + (wn * 64 + la) * 128;

  for (int kc = 0; kc < DIM; kc += 64) {
    __syncthreads();
    #pragma unroll
    for (int i = 0; i < 4; i++)
      gld16(eb + gb + kc + (size_t)(i * 32) * DIM, lb0 + i * 4096);
    {
      const float4* zp = reinterpret_cast<const float4*>(zsrc + kc);
      float4 va[8];
      #pragma unroll
      for (int j = 0; j < 8; j++) va[j] = zp[j];
      #pragma unroll
      for (int j = 0; j < 4; j++) {
        short8 w;
        w[0] = (short)bf16rne(va[2 * j].x);
        w[1] = (short)bf16rne(va[2 * j].y);
        w[2] = (short)bf16rne(va[2 * j].z);
        w[3] = (short)bf16rne(va[2 * j].w);
        w[4] = (short)bf16rne(va[2 * j + 1].x);
        w[5] = (short)bf16rne(va[2 * j + 1].y);
        w[6] = (short)bf16rne(va[2 * j + 1].z);
        w[7] = (short)bf16rne(va[2 * j + 1].w);
        *reinterpret_cast<short8*>(aw + (((ah << 2) + j) ^ akey) * 16) = w;
      }
    }
    __syncthreads();
    #pragma unroll
    for (int ks = 0; ks < 2; ks++) {
      const int q = ((ks * 4 + lq) ^ key) * 16;
      short8 a[4], b[4];
      #pragma unroll
      for (int f = 0; f < 4; f++) {
        a[f] = *reinterpret_cast<const short8*>(Abase + f * 2048 + q);
        b[f] = *reinterpret_cast<const short8*>(Bbase + f * 2048 + q);
      }
      #pragma unroll
      for (int fi = 0; fi < 4; fi++)
        #pragma unroll
        for (int fj = 0; fj < 4; fj++)
          acc[fi][fj] = __builtin_amdgcn_mfma_f32_16x16x32_bf16(a[fi], b[fj], acc[fi][fj], 0, 0, 0);
    }
  }

  float e2c[4];
  #pragma unroll
  for (int fj = 0; fj < 4; fj++)
    e2c[fj] = e2[e0 + wn * 64 + fj * 16 + la];

  // ---- epilogue: per-token top-2 within this 128-wide e-tile ----
  const unsigned colbase = (unsigned)(wn * 64 + la);
  #pragma unroll
  for (int fi = 0; fi < 4; fi++) {
    #pragma unroll
    for (int r = 0; r < 4; r++) {
      unsigned b = 0xFFFFFFFFu, s2 = 0xFFFFFFFFu;
      #pragma unroll
      for (int fj = 0; fj < 4; fj++) {
        float sc = fmaf(-2.0f, acc[fi][fj][r], e2c[fj]);
        unsigned e = ((pk32(sc) >> 13) << 7) | (colbase + (unsigned)(fj * 16));
        mrg1(b, s2, e);
      }
      #pragma unroll
      for (int off = 1; off < 4; off <<= 1) {
        unsigned ob = __shfl_xor(b, off, 64);
        unsigned os = __shfl_xor(s2, off, 64);
        mrg2(b, s2, ob, os);
      }
      if ((la & 3) == 0) {
        int tl = wm * 64 + fi * 16 + (lq << 2) + r;
        int slot = wn * 4 + (la >> 2);
        sbuf[tl][slot] = b;
        ssec[tl][slot] = s2;
      }
    }
  }
  __syncthreads();
  if (tid < 128) {
    unsigned B = 0xFFFFFFFFu, S = 0xFFFFFFFFu;
    #pragma unroll
    for (int p = 0; p < 8; p++) mrg2(B, S, sbuf[tid][p], ssec[tid][p]);
    best2[(size_t)blockIdx.y * NTOK + t0 + tid] = ((unsigned long long)B << 32) | S;
  }
}

// ---------------- K3a: merge 64 tiles/token; build in-band masks -------------
// Ambiguous tokens emit {token, maskA, maskB}: maskA = tiles whose stored
// BEST is in the EPSF band (exact-check that entry); maskB = tiles whose
// stored SECOND is in band (possible hidden rank-3 -> exact-scan whole tile).
__global__ __launch_bounds__(256) void vq_reduce(const unsigned long long* __restrict__ best2,
                                                 unsigned* __restrict__ winners,
                                                 unsigned* __restrict__ work,
                                                 unsigned long long* __restrict__ cmask) {
  int t = blockIdx.x * 256 + threadIdx.x;
  unsigned b = 0xFFFFFFFFu, s = 0xFFFFFFFFu;
  int bey = 0;
  #pragma unroll 8
  for (int ey = 0; ey < 64; ey++) {
    unsigned long long v = best2[(size_t)ey * NTOK + t];
    unsigned hb = (unsigned)(v >> 32), lb = (unsigned)v;
    if (hb < b) { s = b; b = hb; bey = ey; }
    else if (hb < s) { s = hb; }
    if (lb < s) s = lb;          // lb >= hb by construction
  }
  float fb = upk32((b >> 7) << 13);
  float fs = upk32((s >> 7) << 13);
  if (fs > fb + DSELQ) { winners[t] = (unsigned)(bey * 128) + (b & 127u); return; }

  unsigned bandkey = pk32(fb + EPSF) >> 13;
  unsigned long long mA = 0ull, mB = 0ull;
  #pragma unroll 8
  for (int ey = 0; ey < 64; ey++) {
    unsigned long long v = best2[(size_t)ey * NTOK + t];
    if (((unsigned)(v >> 32) >> 7) <= bandkey) mA |= (1ull << ey);
    if ((((unsigned)v) >> 7) <= bandkey)       mB |= (1ull << ey);
  }
  unsigned w = atomicAdd(&work[0], 1u);
  work[1 + w] = (unsigned)t;
  cmask[2 * (size_t)w] = mA;
  cmask[2 * (size_t)w + 1] = mB;
}

// ---------------- K3b: exact fp32 resolution for ambiguous tokens ------------
// One wave per token.  Lane ly owns e-tile ly: if maskA bit -> exact-check its
// stored best entry (one best2 load per in-band lane only).  Each maskB tile
// is exact-scanned by the whole wave (128 codes = 2 rounds) -- covers any
// hidden rank-3 candidate.  No full-codebook scan exists or is needed.
__global__ __launch_bounds__(64) void vq_chain(const float* __restrict__ z,
                                               const float* __restrict__ emb,
                                               const float* __restrict__ z2,
                                               const float* __restrict__ e2,
                                               const unsigned long long* __restrict__ best2,
                                               const unsigned* __restrict__ work,
                                               const unsigned long long* __restrict__ cmask,
                                               unsigned* __restrict__ winners) {
  __shared__ float zr[256];
  const int lane = threadIdx.x;
  const int nw = (int)work[0];

  for (int i = blockIdx.x; i < nw; i += gridDim.x) {
    int t = (int)work[1 + i];
    float4 zv = reinterpret_cast<const float4*>(z + (size_t)t * DIM)[lane];
    *reinterpret_cast<float4*>(&zr[lane * 4]) = zv;
    __syncthreads();
    const float z2t = z2[t];
    const unsigned long long mA = cmask[2 * (size_t)i];
    unsigned long long mB = cmask[2 * (size_t)i + 1];

    unsigned long long best = ~0ull;
    if ((mA >> lane) & 1ull) {
      unsigned long long v = best2[(size_t)lane * NTOK + t];
      int cidx = lane * 128 + (int)((unsigned)(v >> 32) & 127u);
      best = exdot(emb, zr, z2t, e2, cidx);
    }
    while (mB) {
      int ty = __ffsll((long long)mB) - 1;
      mB &= mB - 1;
      #pragma unroll
      for (int half = 0; half < 2; half++) {
        int cidx = ty * 128 + half * 64 + lane;
        unsigned long long kk = exdot(emb, zr, z2t, e2, cidx);
        best = kk < best ? kk : best;
      }
    }
    #pragma unroll
    for (int off = 32; off > 0; off >>= 1) {
      unsigned long long o = __shfl_xor(best, off, 64);
      best = o < best ? o : best;
    }
    if (lane == 0) winners[t] = (unsigned)(best & 0xffffffffu);
    __syncthreads();
  }
}

// ---------------- K4: gather zq = emb[winner], idx, loss ---------------------
__global__ __launch_bounds__(256) void vq_emit(const float* __restrict__ z,
                                               const float* __restrict__ emb,
                                               const unsigned* __restrict__ winners,
                                               float* __restrict__ out_zq,
                                               float* __restrict__ out_loss,
                                               float* __restrict__ out_idx) {
  __shared__ float lsum[4];
  const int wid = threadIdx.x >> 6;
  const int lane = threadIdx.x & 63;
  const int tbase = blockIdx.x * 16 + wid * 4;
  float s_acc = 0.0f;
  #pragma unroll
  for (int it = 0; it < 4; it++) {
    int t = tbase + it;
    unsigned idx = winners[t];
    float4 e = reinterpret_cast<const float4*>(emb + (size_t)idx * DIM)[lane];
    float4 zz = reinterpret_cast<const float4*>(z + (size_t)t * DIM)[lane];
    reinterpret_cast<float4*>(out_zq + (size_t)t * DIM)[lane] = e;
    float dx = e.x - zz.x, dy = e.y - zz.y, dz = e.z - zz.z, dw = e.w - zz.w;
    s_acc += dx * dx + dy * dy + dz * dz + dw * dw;
    if (lane == 0) out_idx[t] = (float)idx;
  }
  #pragma unroll
  for (int off = 32; off > 0; off >>= 1) s_acc += __shfl_down(s_acc, off, 64);
  if (lane == 0) lsum[wid] = s_acc;
  __syncthreads();
  if (threadIdx.x == 0) {
    float tot = (lsum[0] + lsum[1] + lsum[2] + lsum[3]) * (1.25f / 8388608.0f);
    atomicAdd(out_loss, tot);
  }
}

// ====================== round-3 verified fallback path =======================
#define BT 128
#define BE 128
#define BK 32
#define LDW 132

__global__ __launch_bounds__(256) void fb_init(const float* __restrict__ z,
                                               const float* __restrict__ emb,
                                               float* __restrict__ e2,
                                               float* __restrict__ z2,
                                               unsigned long long* __restrict__ k1,
                                               float* __restrict__ loss_slot) {
  int gid = blockIdx.x * 256 + threadIdx.x;
  if (gid < NTOK) k1[gid] = ~0ull;
  if (gid == 0) loss_slot[0] = 0.0f;
  int wave = gid >> 6;
  int lane = threadIdx.x & 63;
  int row = wave * 16 + (lane >> 2);
  int sub = lane & 3;
  int q = sub & 1, h = sub >> 1;
  const float* src = (row < NTOK) ? (z + (size_t)row * DIM)
                                  : (emb + (size_t)(row - NTOK) * DIM);
  const float4* p = reinterpret_cast<const float4*>(src + h * 128 + q * 4);
  float r0, r1, r2, r3, s;
  {
    #pragma clang fp contract(off)
    r0 = 0.0f; r1 = 0.0f; r2 = 0.0f; r3 = 0.0f;
    #pragma unroll
    for (int t = 0; t < 16; t++) {
      float4 v = p[2 * t];
      float q0 = v.x * v.x, q1 = v.y * v.y, q2 = v.z * v.z, q3 = v.w * v.w;
      r0 = r0 + q0; r1 = r1 + q1; r2 = r2 + q2; r3 = r3 + q3;
    }
    s = (r0 + r1) + (r2 + r3);
    s = s + __shfl_xor(s, 1, 64);
    s = s + __shfl_xor(s, 2, 64);
  }
  if (sub == 0) {
    if (row < NTOK) z2[row] = s;
    else            e2[row - NTOK] = s;
  }
}

__global__ __launch_bounds__(256, 4) void fb_score(const float* __restrict__ z,
                                                   const float* __restrict__ emb,
                                                   const float* __restrict__ e2,
                                                   const float* __restrict__ z2,
                                                   unsigned long long* __restrict__ k1) {
  __shared__ float As[BK][LDW];
  __shared__ float Bs[BK][LDW];
  __shared__ unsigned long long mkey[BT];
  const int tid = threadIdx.x;
  const int t0 = blockIdx.x * BT;
  const int e0 = blockIdx.y * BE;
  const int tx = tid & 15;
  const int ty = tid >> 4;
  if (tid < BT) mkey[tid] = ~0ull;
  float acc[8][8];
  #pragma unroll
  for (int i = 0; i < 8; i++)
    #pragma unroll
    for (int j = 0; j < 8; j++) acc[i][j] = 0.0f;
  const float* __restrict__ zt = z + (size_t)t0 * DIM;
  const float* __restrict__ et = emb + (size_t)e0 * DIM;
  for (int kc = 0; kc < DIM; kc += BK) {
    __syncthreads();
    #pragma unroll
    for (int i = 0; i < 4; i++) {
      int f = tid + i * 256;
      int row = f >> 3;
      int kq = f & 7;
      const float4 va = *reinterpret_cast<const float4*>(zt + row * DIM + kc + kq * 4);
      const float4 vb = *reinterpret_cast<const float4*>(et + row * DIM + kc + kq * 4);
      int k = kq * 4;
      As[k + 0][row] = va.x * 2.0f; As[k + 1][row] = va.y * 2.0f;
      As[k + 2][row] = va.z * 2.0f; As[k + 3][row] = va.w * 2.0f;
      Bs[k + 0][row] = vb.x; Bs[k + 1][row] = vb.y;
      Bs[k + 2][row] = vb.z; Bs[k + 3][row] = vb.w;
    }
    __syncthreads();
    #pragma unroll 4
    for (int k = 0; k < BK; k++) {
      float a[8], b[8];
      *(float4*)&a[0] = *(const float4*)&As[k][ty * 8];
      *(float4*)&a[4] = *(const float4*)&As[k][ty * 8 + 4];
      *(float4*)&b[0] = *(const float4*)&Bs[k][tx * 8];
      *(float4*)&b[4] = *(const float4*)&Bs[k][tx * 8 + 4];
      #pragma unroll
      for (int i = 0; i < 8; i++)
        #pragma unroll
        for (int j = 0; j < 8; j++)
          acc[i][j] = fmaf(a[i], b[j], acc[i][j]);
    }
  }
  float e2c[8], z2t[8];
  *(float4*)&e2c[0] = *(const float4*)(e2 + e0 + tx * 8);
  *(float4*)&e2c[4] = *(const float4*)(e2 + e0 + tx * 8 + 4);
  *(float4*)&z2t[0] = *(const float4*)(z2 + t0 + ty * 8);
  *(float4*)&z2t[4] = *(const float4*)(z2 + t0 + ty * 8 + 4);
  {
    #pragma clang fp contract(off)
    #pragma unroll
    for (int i = 0; i < 8; i++) {
      int trow = ty * 8 + i;
      unsigned long long best = ~0ull;
      #pragma unroll
      for (int j = 0; j < 8; j++) {
        float t1 = z2t[i] - acc[i][j];
        float s = t1 + e2c[j];
        unsigned long long kk = pk64(s, e0 + tx * 8 + j);
        best = kk < best ? kk : best;
      }
      atomicMin(&mkey[trow], best);
    }
  }
  __syncthreads();
  if (tid < BT) atomicMin(&k1[t0 + tid], mkey[tid]);
}

__global__ __launch_bounds__(256) void fb_out(const float* __restrict__ z,
                                              const float* __restrict__ emb,
                                              const unsigned long long* __restrict__ k1,
                                              float* __restrict__ out_zq,
                                              float* __restrict__ out_loss,
                                              float* __restrict__ out_idx) {
  __shared__ float lsum[4];
  const int wid = threadIdx.x >> 6;
  const int lane = threadIdx.x & 63;
  const int tbase = blockIdx.x * 16 + wid * 4;
  float s_acc = 0.0f;
  #pragma unroll
  for (int it = 0; it < 4; it++) {
    int t = tbase + it;
    unsigned idx = (unsigned)(k1[t] & 0xffffffffu);
    float4 e = reinterpret_cast<const float4*>(emb + (size_t)idx * DIM)[lane];
    float4 zz = reinterpret_cast<const float4*>(z + (size_t)t * DIM)[lane];
    reinterpret_cast<float4*>(out_zq + (size_t)t * DIM)[lane] = e;
    float dx = e.x - zz.x, dy = e.y - zz.y, dz = e.z - zz.z, dw = e.w - zz.w;
    s_acc += dx * dx + dy * dy + dz * dz + dw * dw;
    if (lane == 0) out_idx[t] = (float)idx;
  }
  #pragma unroll
  for (int off = 32; off > 0; off >>= 1) s_acc += __shfl_down(s_acc, off, 64);
  if (lane == 0) lsum[wid] = s_acc;
  __syncthreads();
  if (threadIdx.x == 0) {
    float tot = (lsum[0] + lsum[1] + lsum[2] + lsum[3]) * (1.25f / 8388608.0f);
    atomicAdd(out_loss, tot);
  }
}

// ============================== launcher =====================================
extern "C" void kernel_launch(void* const* d_in, const int* in_sizes, int n_in,
                              void* d_out, int out_size, void* d_ws, size_t ws_size,
                              hipStream_t stream) {
  const float* z = (const float*)d_in[0];
  const float* emb = (const float*)d_in[1];
  float* out = (float*)d_out;
  float* out_zq = out;
  float* out_loss = out + (size_t)NTOK * DIM;
  float* out_idx = out_loss + 1;

  // ws: e2 | z2 | best2[64][NTOK]u64 | work(1+NTOK) | winners | cmask | eb
  const size_t OFF_Z2   = 32768;
  const size_t OFF_B2   = 163840;
  const size_t OFF_WORK = OFF_B2 + (size_t)64 * NTOK * 8;      // 16941056
  const size_t OFF_WIN  = OFF_WORK + 4 + 4 * (size_t)NTOK;     // 17072132
  const size_t OFF_CM   = (OFF_WIN + 4 * (size_t)NTOK + 15) & ~(size_t)15;  // 17203216
  const size_t OFF_EB   = OFF_CM + (size_t)NTOK * 16;          // 17727504
  const size_t REQ      = OFF_EB + (size_t)NE * DIM * 2;       // 21921808

  if (ws_size >= REQ) {
    float* e2 = (float*)d_ws;
    float* z2 = (float*)((char*)d_ws + OFF_Z2);
    unsigned long long* best2 = (unsigned long long*)((char*)d_ws + OFF_B2);
    unsigned* work = (unsigned*)((char*)d_ws + OFF_WORK);
    unsigned* winners = (unsigned*)((char*)d_ws + OFF_WIN);
    unsigned long long* cmask = (unsigned long long*)((char*)d_ws + OFF_CM);
    unsigned short* eb = (unsigned short*)((char*)d_ws + OFF_EB);

    hipLaunchKernelGGL(vq_prep, dim3(640), dim3(256), 0, stream,
                       z, emb, e2, z2, work, eb, out_loss);
    hipLaunchKernelGGL(vq_score, dim3(NTOK / 128, NE / 128), dim3(256), 0, stream,
                       z, eb, e2, best2);
    hipLaunchKernelGGL(vq_reduce, dim3(NTOK / 256), dim3(256), 0, stream,
                       best2, winners, work, cmask);
    hipLaunchKernelGGL(vq_chain, dim3(4096), dim3(64), 0, stream,
                       z, emb, z2, e2, best2, work, cmask, winners);
    hipLaunchKernelGGL(vq_emit, dim3(NTOK / 16), dim3(256), 0, stream,
                       z, emb, winners, out_zq, out_loss, out_idx);
  } else {
    float* e2 = (float*)d_ws;
    float* z2 = (float*)((char*)d_ws + 32768);
    unsigned long long* k1 = (unsigned long long*)((char*)d_ws + 262144);
    hipLaunchKernelGGL(fb_init, dim3(640), dim3(256), 0, stream,
                       z, emb, e2, z2, k1, out_loss);
    hipLaunchKernelGGL(fb_score, dim3(NTOK / BT, NE / BE), dim3(256), 0, stream,
                       z, emb, e2, z2, k1);
    hipLaunchKernelGGL(fb_out, dim3(NTOK / 16), dim3(256), 0, stream,
                       z, emb, k1, out_zq, out_loss, out_idx);
  }
}

// Round 5
// 867.444 us; speedup vs baseline: 5.1228x; 1.0464x over previous
//
#include <hip/hip_runtime.h>

#define NTOK  32768
#define NE    8192
#define DIM   256
#define EPSF  5.0e-4f   // candidate band slack (>= 2*delta bound 3.2e-4 + key quantum)
#define DSELQ 4.8e-4f   // ambiguity bound on quantized keys (4.5e-4 + quantum slop)

typedef __attribute__((ext_vector_type(8))) short short8;
typedef __attribute__((ext_vector_type(4))) float f32x4;

static __device__ __forceinline__ unsigned pk32(float f) {
  unsigned u = __float_as_uint(f);
  return (u & 0x80000000u) ? ~u : (u | 0x80000000u);
}
static __device__ __forceinline__ float upk32(unsigned p) {
  unsigned u = (p & 0x80000000u) ? (p & 0x7fffffffu) : ~p;
  return __uint_as_float(u);
}
static __device__ __forceinline__ unsigned long long pk64(float s, int idx) {
  return ((unsigned long long)pk32(s) << 32) | (unsigned)idx;
}
static __device__ __forceinline__ unsigned short bf16rne(float f) {
  unsigned u = __float_as_uint(f);
  unsigned r = u + 0x7fffu + ((u >> 16) & 1u);
  return (unsigned short)(r >> 16);
}
static __device__ __forceinline__ void gld16(const void* g, void* l) {
  __builtin_amdgcn_global_load_lds(
      (const __attribute__((address_space(1))) unsigned int*)g,
      (__attribute__((address_space(3))) unsigned int*)l, 16, 0, 0);
}
// merge candidate x into sorted pair (b,s)
static __device__ __forceinline__ void mrg1(unsigned& b, unsigned& s, unsigned x) {
  if (x < b) { s = b; b = x; } else if (x < s) { s = x; }
}
// merge sorted pair (pb,ps) into (b,s)
static __device__ __forceinline__ void mrg2(unsigned& b, unsigned& s, unsigned pb, unsigned ps) {
  unsigned nb = b < pb ? b : pb;
  unsigned mx = b < pb ? pb : b;
  unsigned mn = s < ps ? s : ps;
  s = mx < mn ? mx : mn;
  b = nb;
}
// exact fp32 score key for code cidx vs LDS-staged z row (k-order fmaf chain,
// identical arithmetic to the round-1-verified scalar version; float4 loads)
static __device__ __forceinline__ unsigned long long exdot(const float* __restrict__ emb,
                                                           const float* zr, float z2t,
                                                           const float* __restrict__ e2,
                                                           int cidx) {
  {
    #pragma clang fp contract(off)
    const float* er = emb + (size_t)cidx * DIM;
    float m = 0.0f;
    #pragma unroll 8
    for (int k4 = 0; k4 < DIM / 4; k4++) {
      float4 v = reinterpret_cast<const float4*>(er)[k4];
      m = fmaf(2.0f * zr[4 * k4 + 0], v.x, m);
      m = fmaf(2.0f * zr[4 * k4 + 1], v.y, m);
      m = fmaf(2.0f * zr[4 * k4 + 2], v.z, m);
      m = fmaf(2.0f * zr[4 * k4 + 3], v.w, m);
    }
    float sc = (z2t - m) + e2[cidx];
    return pk64(sc, cidx);
  }
}

// ---------------- K1: prep (z2/e2 pairwise-exact, eb bf16 copy, inits) -------
__global__ __launch_bounds__(256) void vq_prep(const float* __restrict__ z,
                                               const float* __restrict__ emb,
                                               float* __restrict__ e2,
                                               float* __restrict__ z2,
                                               unsigned* __restrict__ work,
                                               unsigned short* __restrict__ eb,
                                               float* __restrict__ loss_slot) {
  int gid = blockIdx.x * 256 + threadIdx.x;
  if (gid == 0) { loss_slot[0] = 0.0f; work[0] = 0u; }

  int wave = gid >> 6;
  int lane = threadIdx.x & 63;
  int row = wave * 16 + (lane >> 2);            // 0..40959
  int sub = lane & 3;
  int q = sub & 1, h = sub >> 1;

  const bool is_e = (row >= NTOK);
  const float* src = is_e ? (emb + (size_t)(row - NTOK) * DIM)
                          : (z + (size_t)row * DIM);
  unsigned short* dst = is_e ? (eb + (size_t)(row - NTOK) * DIM) : (unsigned short*)0;
  const float4* p = reinterpret_cast<const float4*>(src + h * 128 + q * 4);

  float r0, r1, r2, r3, s;
  {
    #pragma clang fp contract(off)
    r0 = 0.0f; r1 = 0.0f; r2 = 0.0f; r3 = 0.0f;
    #pragma unroll
    for (int t = 0; t < 16; t++) {
      float4 v = p[2 * t];
      if (is_e) {
        ushort4 w;
        w.x = bf16rne(v.x); w.y = bf16rne(v.y); w.z = bf16rne(v.z); w.w = bf16rne(v.w);
        *reinterpret_cast<ushort4*>(dst + h * 128 + q * 4 + t * 8) = w;
      }
      float q0 = v.x * v.x, q1 = v.y * v.y, q2 = v.z * v.z, q3 = v.w * v.w;
      r0 = r0 + q0; r1 = r1 + q1; r2 = r2 + q2; r3 = r3 + q3;
    }
    s = (r0 + r1) + (r2 + r3);
    s = s + __shfl_xor(s, 1, 64);
    s = s + __shfl_xor(s, 2, 64);
  }
  if (sub == 0) {
    if (is_e) e2[row - NTOK] = s;
    else      z2[row] = s;
  }
}

// ---------------- K2: single-pass bf16 MFMA scoring, top-2 per 128-tile ------
// Grid is (e-tiles, t-tiles) with e fastest: the 64 consecutive blocks sharing
// one fp32 z-tile (128 KB) are adjacent in dispatch order, so per-XCD L2 holds
// ~8 z-tiles (1 MB) + the eb slab -> operand re-reads stay in L2 instead of
// flooding L3/HBM (round-4 lesson: FETCH 630 MB, fetch-bound at 733 us).
__global__ __launch_bounds__(256, 2) void vq_score(const float* __restrict__ z,
                                                   const unsigned short* __restrict__ eb,
                                                   const float* __restrict__ e2,
                                                   unsigned long long* __restrict__ best2) {
  __shared__ unsigned short Ab[128 * 64];
  __shared__ unsigned short Bb[128 * 64];
  __shared__ unsigned sbuf[128][8];
  __shared__ unsigned ssec[128][8];

  const int tid = threadIdx.x;
  const int t0 = blockIdx.y * 128;
  const int e0 = blockIdx.x * 128;
  const int lane = tid & 63;
  const int wv = tid >> 6;
  const int wm = wv & 1, wn = wv >> 1;

  f32x4 acc[4][4];
  #pragma unroll
  for (int i = 0; i < 4; i++)
    #pragma unroll
    for (int j = 0; j < 4; j++) acc[i][j] = (f32x4)0.0f;

  // B staging (gld16, linear LDS dest + inverse-swizzled global source):
  const int r0 = tid >> 3;
  const int sq = (tid & 7) ^ (r0 & 7);
  const size_t gb = (size_t)(e0 + r0) * DIM + sq * 8;
  char* lb0 = (char*)Bb + tid * 16;

  // A staging (fp32 z -> bf16, per-lane swizzled ds_write_b128):
  const int ar = tid >> 1;            // 0..127 token row
  const int ah = tid & 1;             // k-half (32 floats)
  const float* zsrc = z + (size_t)(t0 + ar) * DIM + ah * 32;
  char* aw = (char*)Ab + ar * 128;
  const int akey = ar & 7;

  // fragment reads: row = w*64 + f*16 + la  ->  row&7 == la&7 (loop-invariant)
  const int la = lane & 15, lq = lane >> 4;
  const int key = la & 7;
  const char* Abase = (const char*)Ab + (wm * 64 + la) * 128;
  const char* Bbase = (const char*)Bb + (wn * 64 + la) * 128;

  for (int kc = 0; kc < DIM; kc += 64) {
    __syncthreads();
    #pragma unroll
    for (int i = 0; i < 4; i++)
      gld16(eb + gb + kc + (size_t)(i * 32) * DIM, lb0 + i * 4096);
    {
      const float4* zp = reinterpret_cast<const float4*>(zsrc + kc);
      float4 va[8];
      #pragma unroll
      for (int j = 0; j < 8; j++) va[j] = zp[j];
      #pragma unroll
      for (int j = 0; j < 4; j++) {
        short8 w;
        w[0] = (short)bf16rne(va[2 * j].x);
        w[1] = (short)bf16rne(va[2 * j].y);
        w[2] = (short)bf16rne(va[2 * j].z);
        w[3] = (short)bf16rne(va[2 * j].w);
        w[4] = (short)bf16rne(va[2 * j + 1].x);
        w[5] = (short)bf16rne(va[2 * j + 1].y);
        w[6] = (short)bf16rne(va[2 * j + 1].z);
        w[7] = (short)bf16rne(va[2 * j + 1].w);
        *reinterpret_cast<short8*>(aw + (((ah << 2) + j) ^ akey) * 16) = w;
      }
    }
    __syncthreads();
    #pragma unroll
    for (int ks = 0; ks < 2; ks++) {
      const int q = ((ks * 4 + lq) ^ key) * 16;
      short8 a[4], b[4];
      #pragma unroll
      for (int f = 0; f < 4; f++) {
        a[f] = *reinterpret_cast<const short8*>(Abase + f * 2048 + q);
        b[f] = *reinterpret_cast<const short8*>(Bbase + f * 2048 + q);
      }
      #pragma unroll
      for (int fi = 0; fi < 4; fi++)
        #pragma unroll
        for (int fj = 0; fj < 4; fj++)
          acc[fi][fj] = __builtin_amdgcn_mfma_f32_16x16x32_bf16(a[fi], b[fj], acc[fi][fj], 0, 0, 0);
    }
  }

  float e2c[4];
  #pragma unroll
  for (int fj = 0; fj < 4; fj++)
    e2c[fj] = e2[e0 + wn * 64 + fj * 16 + la];

  // ---- epilogue: per-token top-2 within this 128-wide e-tile ----
  const unsigned colbase = (unsigned)(wn * 64 + la);
  #pragma unroll
  for (int fi = 0; fi < 4; fi++) {
    #pragma unroll
    for (int r = 0; r < 4; r++) {
      unsigned b = 0xFFFFFFFFu, s2 = 0xFFFFFFFFu;
      #pragma unroll
      for (int fj = 0; fj < 4; fj++) {
        float sc = fmaf(-2.0f, acc[fi][fj][r], e2c[fj]);
        unsigned e = ((pk32(sc) >> 13) << 7) | (colbase + (unsigned)(fj * 16));
        mrg1(b, s2, e);
      }
      #pragma unroll
      for (int off = 1; off < 4; off <<= 1) {
        unsigned ob = __shfl_xor(b, off, 64);
        unsigned os = __shfl_xor(s2, off, 64);
        mrg2(b, s2, ob, os);
      }
      if ((la & 3) == 0) {
        int tl = wm * 64 + fi * 16 + (lq << 2) + r;
        int slot = wn * 4 + (la >> 2);
        sbuf[tl][slot] = b;
        ssec[tl][slot] = s2;
      }
    }
  }
  __syncthreads();
  if (tid < 128) {
    unsigned B = 0xFFFFFFFFu, S = 0xFFFFFFFFu;
    #pragma unroll
    for (int p = 0; p < 8; p++) mrg2(B, S, sbuf[tid][p], ssec[tid][p]);
    best2[(size_t)blockIdx.x * NTOK + t0 + tid] = ((unsigned long long)B << 32) | S;
  }
}

// ---------------- K3a: merge 64 tiles/token; build in-band masks -------------
// Ambiguous tokens emit {token, maskA, maskB}: maskA = tiles whose stored
// BEST is in the EPSF band (exact-check that entry); maskB = tiles whose
// stored SECOND is in band (possible hidden rank-3 -> exact-scan whole tile).
__global__ __launch_bounds__(256) void vq_reduce(const unsigned long long* __restrict__ best2,
                                                 unsigned* __restrict__ winners,
                                                 unsigned* __restrict__ work,
                                                 unsigned long long* __restrict__ cmask) {
  int t = blockIdx.x * 256 + threadIdx.x;
  unsigned b = 0xFFFFFFFFu, s = 0xFFFFFFFFu;
  int bey = 0;
  #pragma unroll 8
  for (int ey = 0; ey < 64; ey++) {
    unsigned long long v = best2[(size_t)ey * NTOK + t];
    unsigned hb = (unsigned)(v >> 32), lb = (unsigned)v;
    if (hb < b) { s = b; b = hb; bey = ey; }
    else if (hb < s) { s = hb; }
    if (lb < s) s = lb;          // lb >= hb by construction
  }
  float fb = upk32((b >> 7) << 13);
  float fs = upk32((s >> 7) << 13);
  if (fs > fb + DSELQ) { winners[t] = (unsigned)(bey * 128) + (b & 127u); return; }

  unsigned bandkey = pk32(fb + EPSF) >> 13;
  unsigned long long mA = 0ull, mB = 0ull;
  #pragma unroll 8
  for (int ey = 0; ey < 64; ey++) {
    unsigned long long v = best2[(size_t)ey * NTOK + t];
    if (((unsigned)(v >> 32) >> 7) <= bandkey) mA |= (1ull << ey);
    if ((((unsigned)v) >> 7) <= bandkey)       mB |= (1ull << ey);
  }
  unsigned w = atomicAdd(&work[0], 1u);
  work[1 + w] = (unsigned)t;
  cmask[2 * (size_t)w] = mA;
  cmask[2 * (size_t)w + 1] = mB;
}

// ---------------- K3b: exact fp32 resolution for ambiguous tokens ------------
// One wave per token.  Lane ly owns e-tile ly: if maskA bit -> exact-check its
// stored best entry (one best2 load per in-band lane only).  Each maskB tile
// is exact-scanned by the whole wave (128 codes = 2 rounds) -- covers any
// hidden rank-3 candidate.  No full-codebook scan exists or is needed.
__global__ __launch_bounds__(64) void vq_chain(const float* __restrict__ z,
                                               const float* __restrict__ emb,
                                               const float* __restrict__ z2,
                                               const float* __restrict__ e2,
                                               const unsigned long long* __restrict__ best2,
                                               const unsigned* __restrict__ work,
                                               const unsigned long long* __restrict__ cmask,
                                               unsigned* __restrict__ winners) {
  __shared__ float zr[256];
  const int lane = threadIdx.x;
  const int nw = (int)work[0];

  for (int i = blockIdx.x; i < nw; i += gridDim.x) {
    int t = (int)work[1 + i];
    float4 zv = reinterpret_cast<const float4*>(z + (size_t)t * DIM)[lane];
    *reinterpret_cast<float4*>(&zr[lane * 4]) = zv;
    __syncthreads();
    const float z2t = z2[t];
    const unsigned long long mA = cmask[2 * (size_t)i];
    unsigned long long mB = cmask[2 * (size_t)i + 1];

    unsigned long long best = ~0ull;
    if ((mA >> lane) & 1ull) {
      unsigned long long v = best2[(size_t)lane * NTOK + t];
      int cidx = lane * 128 + (int)((unsigned)(v >> 32) & 127u);
      best = exdot(emb, zr, z2t, e2, cidx);
    }
    while (mB) {
      int ty = __ffsll((long long)mB) - 1;
      mB &= mB - 1;
      #pragma unroll
      for (int half = 0; half < 2; half++) {
        int cidx = ty * 128 + half * 64 + lane;
        unsigned long long kk = exdot(emb, zr, z2t, e2, cidx);
        best = kk < best ? kk : best;
      }
    }
    #pragma unroll
    for (int off = 32; off > 0; off >>= 1) {
      unsigned long long o = __shfl_xor(best, off, 64);
      best = o < best ? o : best;
    }
    if (lane == 0) winners[t] = (unsigned)(best & 0xffffffffu);
    __syncthreads();
  }
}

// ---------------- K4: gather zq = emb[winner], idx, loss ---------------------
__global__ __launch_bounds__(256) void vq_emit(const float* __restrict__ z,
                                               const float* __restrict__ emb,
                                               const unsigned* __restrict__ winners,
                                               float* __restrict__ out_zq,
                                               float* __restrict__ out_loss,
                                               float* __restrict__ out_idx) {
  __shared__ float lsum[4];
  const int wid = threadIdx.x >> 6;
  const int lane = threadIdx.x & 63;
  const int tbase = blockIdx.x * 16 + wid * 4;
  float s_acc = 0.0f;
  #pragma unroll
  for (int it = 0; it < 4; it++) {
    int t = tbase + it;
    unsigned idx = winners[t];
    float4 e = reinterpret_cast<const float4*>(emb + (size_t)idx * DIM)[lane];
    float4 zz = reinterpret_cast<const float4*>(z + (size_t)t * DIM)[lane];
    reinterpret_cast<float4*>(out_zq + (size_t)t * DIM)[lane] = e;
    float dx = e.x - zz.x, dy = e.y - zz.y, dz = e.z - zz.z, dw = e.w - zz.w;
    s_acc += dx * dx + dy * dy + dz * dz + dw * dw;
    if (lane == 0) out_idx[t] = (float)idx;
  }
  #pragma unroll
  for (int off = 32; off > 0; off >>= 1) s_acc += __shfl_down(s_acc, off, 64);
  if (lane == 0) lsum[wid] = s_acc;
  __syncthreads();
  if (threadIdx.x == 0) {
    float tot = (lsum[0] + lsum[1] + lsum[2] + lsum[3]) * (1.25f / 8388608.0f);
    atomicAdd(out_loss, tot);
  }
}

// ====================== round-3 verified fallback path =======================
#define BT 128
#define BE 128
#define BK 32
#define LDW 132

__global__ __launch_bounds__(256) void fb_init(const float* __restrict__ z,
                                               const float* __restrict__ emb,
                                               float* __restrict__ e2,
                                               float* __restrict__ z2,
                                               unsigned long long* __restrict__ k1,
                                               float* __restrict__ loss_slot) {
  int gid = blockIdx.x * 256 + threadIdx.x;
  if (gid < NTOK) k1[gid] = ~0ull;
  if (gid == 0) loss_slot[0] = 0.0f;
  int wave = gid >> 6;
  int lane = threadIdx.x & 63;
  int row = wave * 16 + (lane >> 2);
  int sub = lane & 3;
  int q = sub & 1, h = sub >> 1;
  const float* src = (row < NTOK) ? (z + (size_t)row * DIM)
                                  : (emb + (size_t)(row - NTOK) * DIM);
  const float4* p = reinterpret_cast<const float4*>(src + h * 128 + q * 4);
  float r0, r1, r2, r3, s;
  {
    #pragma clang fp contract(off)
    r0 = 0.0f; r1 = 0.0f; r2 = 0.0f; r3 = 0.0f;
    #pragma unroll
    for (int t = 0; t < 16; t++) {
      float4 v = p[2 * t];
      float q0 = v.x * v.x, q1 = v.y * v.y, q2 = v.z * v.z, q3 = v.w * v.w;
      r0 = r0 + q0; r1 = r1 + q1; r2 = r2 + q2; r3 = r3 + q3;
    }
    s = (r0 + r1) + (r2 + r3);
    s = s + __shfl_xor(s, 1, 64);
    s = s + __shfl_xor(s, 2, 64);
  }
  if (sub == 0) {
    if (row < NTOK) z2[row] = s;
    else            e2[row - NTOK] = s;
  }
}

__global__ __launch_bounds__(256, 4) void fb_score(const float* __restrict__ z,
                                                   const float* __restrict__ emb,
                                                   const float* __restrict__ e2,
                                                   const float* __restrict__ z2,
                                                   unsigned long long* __restrict__ k1) {
  __shared__ float As[BK][LDW];
  __shared__ float Bs[BK][LDW];
  __shared__ unsigned long long mkey[BT];
  const int tid = threadIdx.x;
  const int t0 = blockIdx.x * BT;
  const int e0 = blockIdx.y * BE;
  const int tx = tid & 15;
  const int ty = tid >> 4;
  if (tid < BT) mkey[tid] = ~0ull;
  float acc[8][8];
  #pragma unroll
  for (int i = 0; i < 8; i++)
    #pragma unroll
    for (int j = 0; j < 8; j++) acc[i][j] = 0.0f;
  const float* __restrict__ zt = z + (size_t)t0 * DIM;
  const float* __restrict__ et = emb + (size_t)e0 * DIM;
  for (int kc = 0; kc < DIM; kc += BK) {
    __syncthreads();
    #pragma unroll
    for (int i = 0; i < 4; i++) {
      int f = tid + i * 256;
      int row = f >> 3;
      int kq = f & 7;
      const float4 va = *reinterpret_cast<const float4*>(zt + row * DIM + kc + kq * 4);
      const float4 vb = *reinterpret_cast<const float4*>(et + row * DIM + kc + kq * 4);
      int k = kq * 4;
      As[k + 0][row] = va.x * 2.0f; As[k + 1][row] = va.y * 2.0f;
      As[k + 2][row] = va.z * 2.0f; As[k + 3][row] = va.w * 2.0f;
      Bs[k + 0][row] = vb.x; Bs[k + 1][row] = vb.y;
      Bs[k + 2][row] = vb.z; Bs[k + 3][row] = vb.w;
    }
    __syncthreads();
    #pragma unroll 4
    for (int k = 0; k < BK; k++) {
      float a[8], b[8];
      *(float4*)&a[0] = *(const float4*)&As[k][ty * 8];
      *(float4*)&a[4] = *(const float4*)&As[k][ty * 8 + 4];
      *(float4*)&b[0] = *(const float4*)&Bs[k][tx * 8];
      *(float4*)&b[4] = *(const float4*)&Bs[k][tx * 8 + 4];
      #pragma unroll
      for (int i = 0; i < 8; i++)
        #pragma unroll
        for (int j = 0; j < 8; j++)
          acc[i][j] = fmaf(a[i], b[j], acc[i][j]);
    }
  }
  float e2c[8], z2t[8];
  *(float4*)&e2c[0] = *(const float4*)(e2 + e0 + tx * 8);
  *(float4*)&e2c[4] = *(const float4*)(e2 + e0 + tx * 8 + 4);
  *(float4*)&z2t[0] = *(const float4*)(z2 + t0 + ty * 8);
  *(float4*)&z2t[4] = *(const float4*)(z2 + t0 + ty * 8 + 4);
  {
    #pragma clang fp contract(off)
    #pragma unroll
    for (int i = 0; i < 8; i++) {
      int trow = ty * 8 + i;
      unsigned long long best = ~0ull;
      #pragma unroll
      for (int j = 0; j < 8; j++) {
        float t1 = z2t[i] - acc[i][j];
        float s = t1 + e2c[j];
        unsigned long long kk = pk64(s, e0 + tx * 8 + j);
        best = kk < best ? kk : best;
      }
      atomicMin(&mkey[trow], best);
    }
  }
  __syncthreads();
  if (tid < BT) atomicMin(&k1[t0 + tid], mkey[tid]);
}

__global__ __launch_bounds__(256) void fb_out(const float* __restrict__ z,
                                              const float* __restrict__ emb,
                                              const unsigned long long* __restrict__ k1,
                                              float* __restrict__ out_zq,
                                              float* __restrict__ out_loss,
                                              float* __restrict__ out_idx) {
  __shared__ float lsum[4];
  const int wid = threadIdx.x >> 6;
  const int lane = threadIdx.x & 63;
  const int tbase = blockIdx.x * 16 + wid * 4;
  float s_acc = 0.0f;
  #pragma unroll
  for (int it = 0; it < 4; it++) {
    int t = tbase + it;
    unsigned idx = (unsigned)(k1[t] & 0xffffffffu);
    float4 e = reinterpret_cast<const float4*>(emb + (size_t)idx * DIM)[lane];
    float4 zz = reinterpret_cast<const float4*>(z + (size_t)t * DIM)[lane];
    reinterpret_cast<float4*>(out_zq + (size_t)t * DIM)[lane] = e;
    float dx = e.x - zz.x, dy = e.y - zz.y, dz = e.z - zz.z, dw = e.w - zz.w;
    s_acc += dx * dx + dy * dy + dz * dz + dw * dw;
    if (lane == 0) out_idx[t] = (float)idx;
  }
  #pragma unroll
  for (int off = 32; off > 0; off >>= 1) s_acc += __shfl_down(s_acc, off, 64);
  if (lane == 0) lsum[wid] = s_acc;
  __syncthreads();
  if (threadIdx.x == 0) {
    float tot = (lsum[0] + lsum[1] + lsum[2] + lsum[3]) * (1.25f / 8388608.0f);
    atomicAdd(out_loss, tot);
  }
}

// ============================== launcher =====================================
extern "C" void kernel_launch(void* const* d_in, const int* in_sizes, int n_in,
                              void* d_out, int out_size, void* d_ws, size_t ws_size,
                              hipStream_t stream) {
  const float* z = (const float*)d_in[0];
  const float* emb = (const float*)d_in[1];
  float* out = (float*)d_out;
  float* out_zq = out;
  float* out_loss = out + (size_t)NTOK * DIM;
  float* out_idx = out_loss + 1;

  // ws: e2 | z2 | best2[64][NTOK]u64 | work(1+NTOK) | winners | cmask | eb
  const size_t OFF_Z2   = 32768;
  const size_t OFF_B2   = 163840;
  const size_t OFF_WORK = OFF_B2 + (size_t)64 * NTOK * 8;      // 16941056
  const size_t OFF_WIN  = OFF_WORK + 4 + 4 * (size_t)NTOK;     // 17072132
  const size_t OFF_CM   = (OFF_WIN + 4 * (size_t)NTOK + 15) & ~(size_t)15;  // 17203216
  const size_t OFF_EB   = OFF_CM + (size_t)NTOK * 16;          // 17727504
  const size_t REQ      = OFF_EB + (size_t)NE * DIM * 2;       // 21921808

  if (ws_size >= REQ) {
    float* e2 = (float*)d_ws;
    float* z2 = (float*)((char*)d_ws + OFF_Z2);
    unsigned long long* best2 = (unsigned long long*)((char*)d_ws + OFF_B2);
    unsigned* work = (unsigned*)((char*)d_ws + OFF_WORK);
    unsigned* winners = (unsigned*)((char*)d_ws + OFF_WIN);
    unsigned long long* cmask = (unsigned long long*)((char*)d_ws + OFF_CM);
    unsigned short* eb = (unsigned short*)((char*)d_ws + OFF_EB);

    hipLaunchKernelGGL(vq_prep, dim3(640), dim3(256), 0, stream,
                       z, emb, e2, z2, work, eb, out_loss);
    hipLaunchKernelGGL(vq_score, dim3(NE / 128, NTOK / 128), dim3(256), 0, stream,
                       z, eb, e2, best2);
    hipLaunchKernelGGL(vq_reduce, dim3(NTOK / 256), dim3(256), 0, stream,
                       best2, winners, work, cmask);
    hipLaunchKernelGGL(vq_chain, dim3(4096), dim3(64), 0, stream,
                       z, emb, z2, e2, best2, work, cmask, winners);
    hipLaunchKernelGGL(vq_emit, dim3(NTOK / 16), dim3(256), 0, stream,
                       z, emb, winners, out_zq, out_loss, out_idx);
  } else {
    float* e2 = (float*)d_ws;
    float* z2 = (float*)((char*)d_ws + 32768);
    unsigned long long* k1 = (unsigned long long*)((char*)d_ws + 262144);
    hipLaunchKernelGGL(fb_init, dim3(640), dim3(256), 0, stream,
                       z, emb, e2, z2, k1, out_loss);
    hipLaunchKernelGGL(fb_score, dim3(NTOK / BT, NE / BE), dim3(256), 0, stream,
                       z, emb, e2, z2, k1);
    hipLaunchKernelGGL(fb_out, dim3(NTOK / 16), dim3(256), 0, stream,
                       z, emb, k1, out_zq, out_loss, out_idx);
  }
}